// Round 1
// baseline (1298.211 us; speedup 1.0000x reference)
//
#include <hip/hip_runtime.h>

// ---------------------------------------------------------------------------
// AttentionModule fused pipeline, MI355X (gfx950).
// B=4, N=4096, K=32, C=128, G=32 (4 ch/group), stats reduce over (4ch, N, K).
//
// Pass plan (all f16 MFMA, fp32 accum, GN folded into following conv weights):
//  K0 prep    : zero stats, convert W_grp/W_fo to f16
//  K1 feat    : f1 = relu(W_feat@feat+b)  (B,64,N) fp32  + gn1 stats g0..15
//  K2 gemm    : x1h = relu(W_grp@gf+b)    (B,64,NK) f16  + gn1 stats g16..31
//  K4 fold    : gn1 -> W1p[b] (f16), b1p[b]
//  K5 u       : u[b,n,co] = W1p_lo @ f1 + b1p   (B,N,128) fp32
//  K6 gemm    : x2 = relu(W1p_hi@x1h + u) (B,128,NK) f16 + gn2 stats
//  K3 gemm    : y3 = W_fo@gfo+b (raw)     (B,128,NK) f16 + gn3 stats
//  K7 folds   : gn2 -> W2p[b],b2p[b];  gn3 -> s3,t3
//  K8a gemm   : scores = W2p@x2+b2p -> mask(count) -> softmax(K) -> wgt f16
//               (wgt aliases x2: each WG reads its p-tile before writing it)
//  K8b final  : out[b,c,n] = sum_k relu(s3*y3+t3)*wgt
// ---------------------------------------------------------------------------

#define B_   4
#define N_   4096
#define KK_  32
#define NK_  131072   // N_*KK_
#define C_   128
#define EPSV 1e-5f

typedef _Float16 hf8 __attribute__((ext_vector_type(8)));
typedef _Float16 hf4 __attribute__((ext_vector_type(4)));
typedef float    f4  __attribute__((ext_vector_type(4)));

// ---------------------------------------------------------------------------
// K0: zero stats (3*256 floats contiguous) + fp32->f16 weight conversion
__global__ void prep_k(const float* __restrict__ Wgrp, const float* __restrict__ Wfo,
                       _Float16* __restrict__ Wgrp_h, _Float16* __restrict__ Wfo_h,
                       float* __restrict__ stats)
{
    int tid = blockIdx.x * 256 + threadIdx.x;
    if (tid < 64 * 128)  Wgrp_h[tid] = (_Float16)Wgrp[tid];
    if (tid < 128 * 128) Wfo_h[tid]  = (_Float16)Wfo[tid];
    if (tid < 768)       stats[tid]  = 0.0f;
}

// ---------------------------------------------------------------------------
// K1: f1 = relu(W_feat @ feat + b_feat), fp32 out (B,64,N); gn1 stats groups 0..15
// (broadcast-along-K multiplicity cancels in the mean -> divisor 4*N at fold)
__global__ void feat_k(const float* __restrict__ feat, const float* __restrict__ Wf,
                       const float* __restrict__ bfeat, float* __restrict__ f1r,
                       float* __restrict__ stats1)
{
    __shared__ float fs[128][64];
    __shared__ float gst[32];
    int tid = threadIdx.x, b = blockIdx.y, n0 = blockIdx.x * 64;
    if (tid < 32) gst[tid] = 0.0f;
    for (int i = tid; i < 128 * 64; i += 256) {
        int ci = i >> 6, n = i & 63;
        fs[ci][n] = feat[((size_t)b * 128 + ci) * N_ + n0 + n];
    }
    __syncthreads();
    int n = tid & 63, cb = (tid >> 6) * 16;
    float gs1[4] = {0,0,0,0}, gs2[4] = {0,0,0,0};
    for (int j = 0; j < 16; j++) {
        int c = cb + j;
        float a = bfeat[c];
        #pragma unroll 16
        for (int ci = 0; ci < 128; ci++) a += Wf[c * 128 + ci] * fs[ci][n];
        a = fmaxf(a, 0.0f);
        f1r[((size_t)b * 64 + c) * N_ + n0 + n] = a;
        gs1[j >> 2] += a; gs2[j >> 2] += a * a;
    }
    for (int g = 0; g < 4; g++) {
        atomicAdd(&gst[((cb >> 2) + g) * 2 + 0], gs1[g]);
        atomicAdd(&gst[((cb >> 2) + g) * 2 + 1], gs2[g]);
    }
    __syncthreads();
    if (tid < 32) atomicAdd(&stats1[b * 64 + tid], gst[tid]);
}

// ---------------------------------------------------------------------------
// fold: stats -> per-channel (s,t); optionally fold into conv weights:
//   Wdst[b][co][c] = f16(Wsrc[co][c]*s[c]);  bdst[b][co] = bsrc[co] + sum_c Wsrc*t
// lowcnt: groups<16 use divisor 4N (f1 path), else 4NK
__global__ void fold_k(const float* __restrict__ stats, const float* __restrict__ gw,
                       const float* __restrict__ gb, const float* __restrict__ Wsrc,
                       const float* __restrict__ bsrc, _Float16* __restrict__ Wdst,
                       float* __restrict__ bdst, float* __restrict__ sdst,
                       float* __restrict__ tdst, int lowcnt)
{
    int b = blockIdx.x, tid = threadIdx.x;
    __shared__ float ss[128], st[128];
    if (tid < 128) {
        int c = tid, g = c >> 2;
        float d  = (lowcnt && g < 16) ? (4.0f * N_) : (4.0f * NK_);
        float S1 = stats[(b * 32 + g) * 2], S2 = stats[(b * 32 + g) * 2 + 1];
        float mu = S1 / d;
        float var = fmaxf(S2 / d - mu * mu, 0.0f);
        float s = gw[c] * rsqrtf(var + EPSV);
        float t = gb[c] - mu * s;
        ss[c] = s; st[c] = t;
        if (sdst) { sdst[b * 128 + c] = s; tdst[b * 128 + c] = t; }
    }
    __syncthreads();
    if (Wdst && tid < 128) {
        int co = tid;
        float a = bsrc[co];
        for (int c = 0; c < 128; c++) {
            float w = Wsrc[co * 128 + c];
            a += w * st[c];
            Wdst[((size_t)b * 128 + co) * 128 + c] = (_Float16)(w * ss[c]);
        }
        bdst[b * 128 + co] = a;
    }
}

// ---------------------------------------------------------------------------
// K5: u[b][n][co] = b1p[co] + sum_{c<64} W1p[b][co][c] * f1[b][c][n]   (fp32)
__global__ void upass_k(const float* __restrict__ f1r, const _Float16* __restrict__ W1p,
                        const float* __restrict__ b1p, float* __restrict__ u)
{
    int b = blockIdx.y, n0 = blockIdx.x * 32, tid = threadIdx.x;
    __shared__ float fs[64][33];
    __shared__ _Float16 wl[128][68];
    for (int i = tid; i < 64 * 32; i += 256) {
        int c = i >> 5, n = i & 31;
        fs[c][n] = f1r[((size_t)b * 64 + c) * N_ + n0 + n];
    }
    for (int i = tid; i < 128 * 64; i += 256) {
        int co = i >> 6, c = i & 63;
        wl[co][c] = W1p[((size_t)b * 128 + co) * 128 + c];
    }
    __syncthreads();
    int co = tid & 127, nh = tid >> 7;
    float bb = b1p[b * 128 + co];
    for (int ps = 0; ps < 16; ps++) {
        int n = nh * 16 + ps;
        float a = bb;
        #pragma unroll 16
        for (int c = 0; c < 64; c++) a += (float)wl[co][c] * fs[c][n];
        u[((size_t)b * N_ + n0 + n) * C_ + co] = a;
    }
}

// ---------------------------------------------------------------------------
// The workhorse GEMM: OUT[co][p] = sum_c W[co][c] * X[c][p]  over position tiles.
// Orientation: MFMA D[p][co] (positions=M). X staged to LDS as xs[p][c] via 4x4
// in-register transpose; W B-frags held in VGPRs for the whole kernel.
// EPI: 0 = relu+store f16+stats, 1 = store raw f16+stats, 2 = mask+softmax(K)+store
template<int CIN, int COUT, int TP, bool SRCF32, int EPI, bool HASU,
         int WRS, int WCOFF, int COOFF, bool WPB, bool BPB>
__global__ void __launch_bounds__(256, 2) gemm_k(
    const void* srcv, const _Float16* __restrict__ W, const float* __restrict__ bias,
    _Float16* out, float* __restrict__ stats, const float* __restrict__ u,
    const int* __restrict__ cnt)
{
    constexpr int KC  = CIN / 32;
    constexpr int WCO = (COUT == 128) ? 2 : 1;
    constexpr int WP  = 4 / WCO;
    constexpr int TILES = NK_ / TP;
    constexpr int NGR = TP / 32;

    __shared__ _Float16 xs[TP][CIN + 8];
    __shared__ float bstat[(EPI != 2) ? COUT * 2 : 1];
    __shared__ float uld[HASU ? NGR * COUT : 1];
    __shared__ int   cld[(EPI == 2) ? NGR : 1];

    const int tid  = threadIdx.x;
    const int lane = tid & 63;
    const int wave = tid >> 6;
    const int l15  = lane & 15;
    const int q    = lane >> 4;
    const int wm   = wave % WP;
    const int wn   = wave / WP;
    const int b    = blockIdx.y;

    // persistent W fragments (B operand): bf[nt][kc] lane holds W[co][c0+q*8+j]
    hf8 bf[4][KC];
    const _Float16* Wb = W + (WPB ? (size_t)b * COUT * WRS : 0);
    #pragma unroll
    for (int nt = 0; nt < 4; nt++) {
        int co = wn * 64 + nt * 16 + l15;
        #pragma unroll
        for (int kc = 0; kc < KC; kc++)
            bf[nt][kc] = *(const hf8*)(Wb + (size_t)co * WRS + WCOFF + kc * 32 + q * 8);
    }
    float biasr[4];
    #pragma unroll
    for (int nt = 0; nt < 4; nt++) {
        int co = wn * 64 + nt * 16 + l15;
        biasr[nt] = bias ? bias[(BPB ? b * COUT : 0) + co] : 0.0f;
    }
    if (EPI != 2) for (int i = tid; i < COUT * 2; i += 256) bstat[i] = 0.0f;

    constexpr int TPG = TP / 4;
    constexpr int CQP = 256 / TPG;
    constexpr int PASSES = CIN / (4 * CQP);
    const int tp = tid % TPG;
    const int cq = tid / TPG;

    for (int t = blockIdx.x; t < TILES; t += gridDim.x) {
        const int pbase = t * TP;
        // ---- stage X tile (transpose to xs[p][c]) ----
        #pragma unroll
        for (int ps = 0; ps < PASSES; ps++) {
            int c0 = (ps * CQP + cq) * 4;
            _Float16 hv[4][4];
            if (SRCF32) {
                const float* s = (const float*)srcv;
                #pragma unroll
                for (int r = 0; r < 4; r++) {
                    f4 v = *(const f4*)(s + ((size_t)(b * CIN + c0 + r)) * NK_ + pbase + tp * 4);
                    #pragma unroll
                    for (int i = 0; i < 4; i++) hv[r][i] = (_Float16)v[i];
                }
            } else {
                const _Float16* s = (const _Float16*)srcv;
                #pragma unroll
                for (int r = 0; r < 4; r++) {
                    hf4 v = *(const hf4*)(s + ((size_t)(b * CIN + c0 + r)) * NK_ + pbase + tp * 4);
                    #pragma unroll
                    for (int i = 0; i < 4; i++) hv[r][i] = v[i];
                }
            }
            #pragma unroll
            for (int i = 0; i < 4; i++) {
                hf4 w = { hv[0][i], hv[1][i], hv[2][i], hv[3][i] };
                *(hf4*)&xs[tp * 4 + i][c0] = w;
            }
        }
        if (HASU)
            for (int i = tid; i < NGR * COUT; i += 256) {
                int ni = i / COUT, co = i % COUT;
                uld[ni * COUT + co] = u[((size_t)b * N_ + (pbase >> 5) + ni) * C_ + co];
            }
        if (EPI == 2 && tid < NGR) {
            int c = cnt[b * N_ + (pbase >> 5) + tid];
            cld[tid] = c < 1 ? 1 : c;
        }
        __syncthreads();

        // ---- init acc ----
        f4 acc[4][4];
        #pragma unroll
        for (int mt = 0; mt < 4; mt++)
            #pragma unroll
            for (int nt = 0; nt < 4; nt++) {
                float v;
                if (HASU) v = uld[(wm * 2 + (mt >> 1)) * COUT + wn * 64 + nt * 16 + l15];
                else      v = biasr[nt];
                acc[mt][nt] = f4{v, v, v, v};
            }

        // ---- MFMA main loop ----
        #pragma unroll
        for (int kc = 0; kc < KC; kc++) {
            hf8 af[4];
            #pragma unroll
            for (int mt = 0; mt < 4; mt++)
                af[mt] = *(const hf8*)&xs[wm * 64 + mt * 16 + l15][kc * 32 + q * 8];
            #pragma unroll
            for (int mt = 0; mt < 4; mt++)
                #pragma unroll
                for (int nt = 0; nt < 4; nt++)
                    acc[mt][nt] = __builtin_amdgcn_mfma_f32_16x16x32_f16(
                        af[mt], bf[nt][kc], acc[mt][nt], 0, 0, 0);
        }

        // ---- epilogue ----
        if constexpr (EPI != 2) {
            #pragma unroll
            for (int nt = 0; nt < 4; nt++) {
                int co = wn * 64 + nt * 16 + l15;
                float s1 = 0.0f, s2 = 0.0f;
                #pragma unroll
                for (int mt = 0; mt < 4; mt++) {
                    f4 a = acc[mt][nt];
                    #pragma unroll
                    for (int i = 0; i < 4; i++) {
                        if (EPI == 0) a[i] = fmaxf(a[i], 0.0f);
                        s1 += a[i]; s2 += a[i] * a[i];
                    }
                    hf4 hv = { (_Float16)a[0], (_Float16)a[1], (_Float16)a[2], (_Float16)a[3] };
                    *(hf4*)(out + ((size_t)(b * COUT + co)) * NK_ + pbase + wm * 64 + mt * 16 + q * 4) = hv;
                }
                s1 += __shfl_xor(s1, 16); s1 += __shfl_xor(s1, 32);
                s2 += __shfl_xor(s2, 16); s2 += __shfl_xor(s2, 32);
                if (q == 0) {
                    atomicAdd(&bstat[co * 2 + 0], s1);
                    atomicAdd(&bstat[co * 2 + 1], s2);
                }
            }
        } else {
            // masked softmax over k (32 contiguous positions); wave covers 2 n-groups
            #pragma unroll
            for (int nt = 0; nt < 4; nt++) {
                float mx0 = -3e38f, mx1 = -3e38f;
                #pragma unroll
                for (int mt = 0; mt < 4; mt++) {
                    int cv = cld[wm * 2 + (mt >> 1)];
                    #pragma unroll
                    for (int r = 0; r < 4; r++) {
                        int k = (mt & 1) * 16 + q * 4 + r;
                        float v = acc[mt][nt][r];
                        if (k >= cv) v = -1e9f;
                        acc[mt][nt][r] = v;
                        if (mt < 2) mx0 = fmaxf(mx0, v); else mx1 = fmaxf(mx1, v);
                    }
                }
                mx0 = fmaxf(mx0, __shfl_xor(mx0, 16)); mx0 = fmaxf(mx0, __shfl_xor(mx0, 32));
                mx1 = fmaxf(mx1, __shfl_xor(mx1, 16)); mx1 = fmaxf(mx1, __shfl_xor(mx1, 32));
                float sm0 = 0.0f, sm1 = 0.0f;
                #pragma unroll
                for (int mt = 0; mt < 4; mt++) {
                    float m = (mt < 2) ? mx0 : mx1;
                    #pragma unroll
                    for (int r = 0; r < 4; r++) {
                        float e = __expf(acc[mt][nt][r] - m);
                        acc[mt][nt][r] = e;
                        if (mt < 2) sm0 += e; else sm1 += e;
                    }
                }
                sm0 += __shfl_xor(sm0, 16); sm0 += __shfl_xor(sm0, 32);
                sm1 += __shfl_xor(sm1, 16); sm1 += __shfl_xor(sm1, 32);
                float i0 = 1.0f / sm0, i1 = 1.0f / sm1;
                int co = wn * 64 + nt * 16 + l15;
                #pragma unroll
                for (int mt = 0; mt < 4; mt++) {
                    float inv = (mt < 2) ? i0 : i1;
                    hf4 hv = { (_Float16)(acc[mt][nt][0] * inv), (_Float16)(acc[mt][nt][1] * inv),
                               (_Float16)(acc[mt][nt][2] * inv), (_Float16)(acc[mt][nt][3] * inv) };
                    *(hf4*)(out + ((size_t)(b * COUT + co)) * NK_ + pbase + wm * 64 + mt * 16 + q * 4) = hv;
                }
            }
        }
        __syncthreads();
    }

    if (EPI != 2 && stats) {
        for (int i = tid; i < COUT * 2; i += 256) {
            int co = i >> 1, j = i & 1;
            int g = (co + COOFF) >> 2;
            atomicAdd(&stats[(b * 32 + g) * 2 + j], bstat[i]);
        }
    }
}

// ---------------------------------------------------------------------------
// K8b: out[b][c][n] = sum_k relu(s3*y3 + t3) * wgt   (fully coalesced streams)
__global__ void final_k(const _Float16* __restrict__ y3, const _Float16* __restrict__ wgt,
                        const float* __restrict__ s3, const float* __restrict__ t3,
                        float* __restrict__ outp)
{
    int idx = blockIdx.x * 256 + threadIdx.x;   // (b*128+co)*4096 + n
    int bc = idx >> 12;
    float sc = s3[bc], tc = t3[bc];
    const _Float16* yp = y3 + (size_t)idx * 32;
    const _Float16* wp = wgt + (size_t)idx * 32;
    float accv = 0.0f;
    #pragma unroll
    for (int i = 0; i < 4; i++) {
        hf8 yv = *(const hf8*)(yp + i * 8);
        hf8 wv = *(const hf8*)(wp + i * 8);
        #pragma unroll
        for (int j = 0; j < 8; j++) {
            float g = fmaxf(sc * (float)yv[j] + tc, 0.0f);
            accv += g * (float)wv[j];
        }
    }
    outp[idx] = accv;
}

// ---------------------------------------------------------------------------
extern "C" void kernel_launch(void* const* d_in, const int* in_sizes, int n_in,
                              void* d_out, int out_size, void* d_ws, size_t ws_size,
                              hipStream_t stream)
{
    (void)in_sizes; (void)n_in; (void)out_size; (void)ws_size;
    const float* feat   = (const float*)d_in[0];
    const float* gf     = (const float*)d_in[1];
    const float* gfo    = (const float*)d_in[2];
    const int*   count  = (const int*)d_in[3];
    const float* W_feat = (const float*)d_in[4];
    const float* b_feat = (const float*)d_in[5];
    const float* W_grp  = (const float*)d_in[6];
    const float* b_grp  = (const float*)d_in[7];
    const float* gn1w   = (const float*)d_in[8];
    const float* gn1b   = (const float*)d_in[9];
    const float* W_wc1  = (const float*)d_in[10];
    const float* b_wc1  = (const float*)d_in[11];
    const float* gn2w   = (const float*)d_in[12];
    const float* gn2b   = (const float*)d_in[13];
    const float* W_wc2  = (const float*)d_in[14];
    const float* b_wc2  = (const float*)d_in[15];
    const float* W_fo   = (const float*)d_in[16];
    const float* b_fo   = (const float*)d_in[17];
    const float* gn3w   = (const float*)d_in[18];
    const float* gn3b   = (const float*)d_in[19];
    float* out = (float*)d_out;

    char* ws = (char*)d_ws;
    size_t o = 0;
    auto alloc = [&](size_t bytes) { size_t r = o; o += (bytes + 255) & ~(size_t)255; return r; };
    _Float16* x1h    = (_Float16*)(ws + alloc((size_t)64 * B_ * NK_ * 2));   //  67 MB
    _Float16* x2     = (_Float16*)(ws + alloc((size_t)128 * B_ * NK_ * 2));  // 134 MB (wgt aliases)
    _Float16* y3     = (_Float16*)(ws + alloc((size_t)128 * B_ * NK_ * 2));  // 134 MB
    float*    f1r    = (float*)(ws + alloc((size_t)B_ * 64 * N_ * 4));       //   4 MB
    float*    u      = (float*)(ws + alloc((size_t)B_ * N_ * 128 * 4));      //   8 MB
    float*    stats1 = (float*)(ws + alloc(256 * 4));                        // stats1..3 contiguous
    float*    stats2 = (float*)(ws + alloc(256 * 4));
    float*    stats3 = (float*)(ws + alloc(256 * 4));
    _Float16* Wgrp_h = (_Float16*)(ws + alloc(64 * 128 * 2));
    _Float16* Wfo_h  = (_Float16*)(ws + alloc(128 * 128 * 2));
    _Float16* W1p    = (_Float16*)(ws + alloc((size_t)B_ * 128 * 128 * 2));
    float*    b1p    = (float*)(ws + alloc(B_ * 128 * 4));
    _Float16* W2p    = (_Float16*)(ws + alloc((size_t)B_ * 128 * 128 * 2));
    float*    b2p    = (float*)(ws + alloc(B_ * 128 * 4));
    float*    s3     = (float*)(ws + alloc(B_ * 128 * 4));
    float*    t3     = (float*)(ws + alloc(B_ * 128 * 4));
    _Float16* wgt    = x2;  // alias: softmax kernel reads its x2 tile before storing

    prep_k<<<64, 256, 0, stream>>>(W_grp, W_fo, Wgrp_h, Wfo_h, stats1);
    feat_k<<<dim3(64, B_), 256, 0, stream>>>(feat, W_feat, b_feat, f1r, stats1);
    // K2: x1h = relu(W_grp @ gf + b_grp), gn1 stats groups 16..31
    gemm_k<128, 64, 256, true, 0, false, 128, 0, 64, false, false>
        <<<dim3(128, B_), 256, 0, stream>>>(gf, Wgrp_h, b_grp, x1h, stats1, nullptr, nullptr);
    // fold gn1 -> W1p/b1p
    fold_k<<<B_, 256, 0, stream>>>(stats1, gn1w, gn1b, W_wc1, b_wc1, W1p, b1p, nullptr, nullptr, 1);
    upass_k<<<dim3(128, B_), 256, 0, stream>>>(f1r, W1p, b1p, u);
    // K6: x2 = relu(W1p_hi @ x1h + u), gn2 stats
    gemm_k<64, 128, 128, false, 0, true, 128, 64, 0, true, false>
        <<<dim3(256, B_), 256, 0, stream>>>(x1h, W1p, nullptr, x2, stats2, u, nullptr);
    // K3: y3 = W_fo @ gfo + b_fo (raw), gn3 stats
    gemm_k<128, 128, 128, true, 1, false, 128, 0, 0, false, false>
        <<<dim3(256, B_), 256, 0, stream>>>(gfo, Wfo_h, b_fo, y3, stats3, nullptr, nullptr);
    // folds: gn2 -> W2p/b2p ; gn3 -> s3/t3
    fold_k<<<B_, 256, 0, stream>>>(stats2, gn2w, gn2b, W_wc2, b_wc2, W2p, b2p, nullptr, nullptr, 0);
    fold_k<<<B_, 256, 0, stream>>>(stats3, gn3w, gn3b, nullptr, nullptr, nullptr, nullptr, s3, t3, 0);
    // K8a: scores -> mask -> softmax -> wgt (aliases x2)
    gemm_k<128, 128, 128, false, 2, false, 128, 0, 0, true, true>
        <<<dim3(256, B_), 256, 0, stream>>>(x2, W2p, b2p, wgt, nullptr, nullptr, count);
    // K8b: weighted sum
    final_k<<<(B_ * 128 * N_) / 256, 256, 0, stream>>>(y3, wgt, s3, t3, out);
}